// Round 9
// baseline (270.894 us; speedup 1.0000x reference)
//
#include <hip/hip_runtime.h>
#include <hip/hip_bf16.h>
#include <math.h>

#define NTOK 2048      // N
#define DDIM 512       // D
#define FDIM 2048      // F
#define KNN_K 16
#define ROWS 4096      // B*N

typedef __hip_bfloat16 hb;
typedef unsigned long long ull;
typedef short s8v __attribute__((ext_vector_type(8)));
typedef short s4v __attribute__((ext_vector_type(4)));
typedef float f4v __attribute__((ext_vector_type(4)));

__device__ __forceinline__ float b2f(hb h) { return __bfloat162float(h); }
__device__ __forceinline__ float bits2f(short s) {
    return __uint_as_float(((unsigned int)(unsigned short)s) << 16);
}

__device__ __forceinline__ float ldin(const void* p, size_t i, int f32m) {
    return f32m ? ((const float*)p)[i] : b2f(((const hb*)p)[i]);
}
__device__ __forceinline__ float ld_scalar(const void* p, int f32m) {
    return f32m ? *(const float*)p : b2f(*(const hb*)p);
}
__device__ __forceinline__ short f2bs(float v) {
    hb h = __float2bfloat16(v);
    short s; __builtin_memcpy(&s, &h, 2); return s;
}
__device__ __forceinline__ short hb2s(hb h) {
    short s; __builtin_memcpy(&s, &h, 2); return s;
}

// load 8 consecutive values (f32 or bf16 input), base must be 8-elem aligned
__device__ __forceinline__ void ld8(const void* p, size_t base, int fm, float* o) {
    if (fm) {
        f4v a = *(const f4v*)((const float*)p + base);
        f4v b = *(const f4v*)((const float*)p + base + 4);
        o[0]=a[0]; o[1]=a[1]; o[2]=a[2]; o[3]=a[3];
        o[4]=b[0]; o[5]=b[1]; o[6]=b[2]; o[7]=b[3];
    } else {
        s8v v = *(const s8v*)((const hb*)p + base);
        #pragma unroll
        for (int e = 0; e < 8; ++e) o[e] = bits2f(v[e]);
    }
}

// wave-uniform inline dtype detection; only setup_kernel pays this, publishes fmflag.
__device__ __forceinline__ int detect_fm(const void* x) {
    const unsigned short* u = (const unsigned short*)x;
    const int lane = threadIdx.x & 63;
    int bad = 0;
    #pragma unroll
    for (int t = 0; t < 16; ++t) {
        unsigned short h = u[lane * 16 + t];
        int e = (h >> 7) & 0xFF;
        if (e == 0xFF) bad++;
        else if (e >= 0x8E) bad++;
        else if (e != 0 && e <= 0x66) bad++;
    }
    #pragma unroll
    for (int off = 1; off < 64; off <<= 1) bad += __shfl_xor(bad, off);
    return bad > 100 ? 1 : 0;
}

__device__ __forceinline__ ull shfl_xor_u64(ull x, int mask) {
    unsigned lo = (unsigned)x, hi = (unsigned)(x >> 32);
    lo = __shfl_xor(lo, mask); hi = __shfl_xor(hi, mask);
    return ((ull)hi << 32) | lo;
}

// gelu via sigmoid form: 0.5x(1+tanh(v)) == x*sigmoid(2v)
__device__ __forceinline__ float gelu_f(float x) {
    float u = 1.5957691216057308f * x * (1.f + 0.044715f * x * x);
    return x / (1.f + __expf(-u));
}

// ---------------- transpose tile body ----------------
__device__ __forceinline__ void tr_tile(const void* src, hb* dst, int K, int N,
                                        int k0, int n0, int fm) {
    __shared__ float t[32][33];
    const int tx = threadIdx.x & 31, ty = threadIdx.x >> 5;   // 32 x 8
    #pragma unroll
    for (int r = 0; r < 32; r += 8)
        t[ty + r][tx] = ldin(src, (size_t)(k0 + ty + r) * N + n0 + tx, fm);
    __syncthreads();
    #pragma unroll
    for (int r = 0; r < 32; r += 8)
        dst[(size_t)(n0 + ty + r) * K + k0 + tx] = __float2bfloat16(t[tx][ty + r]);
}

// ---------------- setup: weight transposes + pos split + p2 + spos + LN1 ----------------
__global__ void setup_kernel(const void* __restrict__ pos, const void* __restrict__ x,
                             const void* __restrict__ ln1s, const void* __restrict__ ln1b,
                             const void* __restrict__ Wq, const void* __restrict__ Wk,
                             const void* __restrict__ Wv, const void* __restrict__ Wo,
                             const void* __restrict__ W1, const void* __restrict__ W2,
                             hb* __restrict__ ph, hb* __restrict__ pl,
                             float* __restrict__ p2, float* __restrict__ spos,
                             hb* __restrict__ xnB,
                             hb* __restrict__ WqkvT, hb* __restrict__ WoT,
                             hb* __restrict__ W1T, hb* __restrict__ W2T,
                             int* __restrict__ fmflag) {
    const int fm = detect_fm(x);
    const int bx = blockIdx.x;
    if (bx == 0 && threadIdx.x == 0) *fmflag = fm;
    if (bx < 1024) {
        const int seg = bx >> 8, t = bx & 255;
        const int n0 = (t & 15) * 32, k0 = (t >> 4) * 32;
        const void* src = (seg == 0) ? Wq : (seg == 1) ? Wk : (seg == 2) ? Wv : Wo;
        hb* dst = (seg == 3) ? WoT : (WqkvT + (size_t)seg * 512 * 512);
        tr_tile(src, dst, 512, 512, k0, n0, fm);
    } else if (bx < 3072) {
        const int b = bx - 1024;
        if (b < 1024) {
            const int n0 = (b & 63) * 32, k0 = (b >> 6) * 32;
            tr_tile(W1, W1T, 512, 2048, k0, n0, fm);
        } else {
            const int b2 = b - 1024;
            const int n0 = (b2 & 15) * 32, k0 = (b2 >> 4) * 32;
            tr_tile(W2, W2T, 2048, 512, k0, n0, fm);
        }
    } else {
        const int idx = bx - 3072;
        const int lane = threadIdx.x & 63, wv = threadIdx.x >> 6;
        const int row = idx * 4 + wv;
        const int d0 = lane * 8;
        float pv[8], xv[8];
        ld8(pos, (size_t)row * DDIM + d0, fm, pv);
        ld8(x,   (size_t)row * DDIM + d0, fm, xv);
        s8v phv, plv;
        float s2 = 0.f, s1 = 0.f, sum = 0.f, sq = 0.f;
        #pragma unroll
        for (int e = 0; e < 8; ++e) {
            float v = pv[e];
            hb h = __float2bfloat16(v);
            phv[e] = hb2s(h);
            plv[e] = f2bs(v - b2f(h));
            s2 += v * v; s1 += v;
            sum += xv[e]; sq += xv[e] * xv[e];
        }
        *(s8v*)(ph + (size_t)row * DDIM + d0) = phv;
        *(s8v*)(pl + (size_t)row * DDIM + d0) = plv;
        #pragma unroll
        for (int off = 32; off; off >>= 1) {
            s2 += __shfl_down(s2, off); s1 += __shfl_down(s1, off);
            sum += __shfl_down(sum, off); sq += __shfl_down(sq, off);
        }
        if (lane == 0) { p2[row] = s2; spos[row] = s1; }
        const float ts = __shfl(sum, 0), tq = __shfl(sq, 0);
        const float mean = ts * (1.f / DDIM);
        const float var = tq * (1.f / DDIM) - mean * mean;
        const float rstd = rsqrtf(var + 1e-6f);
        float sv[8], bv2[8];
        ld8(ln1s, d0, fm, sv);
        ld8(ln1b, d0, fm, bv2);
        s8v xo;
        #pragma unroll
        for (int e = 0; e < 8; ++e)
            xo[e] = f2bs(sv[e] * (xv[e] - mean) * rstd + bv2[e]);
        *(s8v*)(xnB + (size_t)row * DDIM + d0) = xo;
    }
}

// ---------------- LayerNorm (internal f32 in), wave-per-row ----------------
__global__ void ln_kernel(const float* __restrict__ xin,
                          const void* __restrict__ s, const void* __restrict__ b,
                          hb* __restrict__ y, const int* __restrict__ fmflag) {
    const int m = *fmflag;
    const int lane = threadIdx.x & 63, wv = threadIdx.x >> 6;
    const int row = blockIdx.x * 4 + wv;
    const int d0 = lane * 8;
    const float* xp = xin + (size_t)row * DDIM + d0;
    f4v a = *(const f4v*)xp, c4 = *(const f4v*)(xp + 4);
    float v[8] = {a[0], a[1], a[2], a[3], c4[0], c4[1], c4[2], c4[3]};
    float sum = 0.f, sq = 0.f;
    #pragma unroll
    for (int e = 0; e < 8; ++e) { sum += v[e]; sq += v[e] * v[e]; }
    #pragma unroll
    for (int off = 32; off; off >>= 1) { sum += __shfl_down(sum, off); sq += __shfl_down(sq, off); }
    const float ts = __shfl(sum, 0), tq = __shfl(sq, 0);
    const float mean = ts * (1.f / DDIM);
    const float var = tq * (1.f / DDIM) - mean * mean;
    const float rstd = rsqrtf(var + 1e-6f);
    float sv[8], bv[8];
    ld8(s, d0, m, sv);
    ld8(b, d0, m, bv);
    s8v o;
    #pragma unroll
    for (int e = 0; e < 8; ++e) o[e] = f2bs(sv[e] * (v[e] - mean) * rstd + bv[e]);
    *(s8v*)(y + (size_t)row * DDIM + d0) = o;
}

// ================ 64x64-tile GEMM: dbuf LDS, ONE barrier per K-step, 4 blocks/CU ================
template<int EPI>
__global__ __launch_bounds__(256, 4)
void gemm64(const hb* __restrict__ A, const hb* __restrict__ Bt,
            const void* __restrict__ bp0, const void* __restrict__ res,
            void* __restrict__ C, int K, int lda, int ldb, int ldc,
            const int* __restrict__ fmflag) {
    constexpr int BK = 64, LDSW = BK + 8;     // 72 shorts/row
    constexpr int MAT = 64 * LDSW;            // 4608 shorts per matrix tile
    __shared__ short Ls[2 * 2 * MAT];         // 36864 B
    const int fm = *fmflag;
    const int tid = threadIdx.x, lane = tid & 63, wave = tid >> 6;
    const int wy = wave >> 1, wx = wave & 1;
    const int m0 = blockIdx.y * 64, n0 = blockIdx.x * 64;
    const int r0 = tid >> 3, c0 = (tid & 7) * 8;
    const int lm = lane & 15, lk = (lane >> 4) * 8;
    f4v acc[2][2];
    #pragma unroll
    for (int i = 0; i < 2; ++i)
        #pragma unroll
        for (int j = 0; j < 2; ++j) acc[i][j] = (f4v){0.f, 0.f, 0.f, 0.f};

    s8v an[2], bn[2];
    #pragma unroll
    for (int g = 0; g < 2; ++g) {
        an[g] = *(const s8v*)(A  + (size_t)(m0 + r0 + 32 * g) * lda + c0);
        bn[g] = *(const s8v*)(Bt + (size_t)(n0 + r0 + 32 * g) * ldb + c0);
    }

    int p = 0;
    for (int k0 = 0; k0 < K; k0 += BK) {
        short* As = Ls + p * (2 * MAT);
        short* Bs = As + MAT;
        #pragma unroll
        for (int g = 0; g < 2; ++g) {
            *(s8v*)(As + (r0 + 32 * g) * LDSW + c0) = an[g];
            *(s8v*)(Bs + (r0 + 32 * g) * LDSW + c0) = bn[g];
        }
        if (k0 + BK < K) {
            const int kn = k0 + BK;
            #pragma unroll
            for (int g = 0; g < 2; ++g) {
                an[g] = *(const s8v*)(A  + (size_t)(m0 + r0 + 32 * g) * lda + kn + c0);
                bn[g] = *(const s8v*)(Bt + (size_t)(n0 + r0 + 32 * g) * ldb + kn + c0);
            }
        }
        __syncthreads();
        #pragma unroll
        for (int kc = 0; kc < BK; kc += 32) {
            s8v af[2], bf[2];
            #pragma unroll
            for (int f = 0; f < 2; ++f) {
                af[f] = *(const s8v*)(As + (wy * 32 + f * 16 + lm) * LDSW + kc + lk);
                bf[f] = *(const s8v*)(Bs + (wx * 32 + f * 16 + lm) * LDSW + kc + lk);
            }
            #pragma unroll
            for (int fi = 0; fi < 2; ++fi)
                #pragma unroll
                for (int fj = 0; fj < 2; ++fj)
                    acc[fi][fj] = __builtin_amdgcn_mfma_f32_16x16x32_bf16(af[fi], bf[fj], acc[fi][fj], 0, 0, 0);
        }
        p ^= 1;
    }

    const int embase = m0 + wy * 32 + (lane >> 4) * 4;
    const int enbase = n0 + wx * 32 + lm;
    #pragma unroll
    for (int fi = 0; fi < 2; ++fi) {
        #pragma unroll
        for (int fj = 0; fj < 2; ++fj) {
            const int n = enbase + fj * 16;
            const float bias = ldin(bp0, n, fm);
            #pragma unroll
            for (int r = 0; r < 4; ++r) {
                const int m = embase + fi * 16 + r;
                float val = acc[fi][fj][r];
                size_t ci = (size_t)m * ldc + n;
                if (EPI == 1) {
                    val += bias + ldin(res, (size_t)m * 512 + n, fm);
                    ((float*)C)[ci] = val;
                } else if (EPI == 2) {
                    val = gelu_f(val + bias);
                    ((hb*)C)[ci] = __float2bfloat16(val);
                } else {
                    val += bias + ((const float*)res)[(size_t)m * 512 + n];
                    if (fm) ((float*)C)[ci] = val;
                    else ((hb*)C)[ci] = __float2bfloat16(val);
                }
            }
        }
    }
}

// ================ fused launch: dist (blocks 0..271, triangular) || qkv GEMM (272..655) ================
// Round-8 WIN: XOR-swizzled LDS, no padding (chunk c of row r at slot c ^ ((r>>1)&3)) —
// qkv_dist dropped out of top-5. LDS 32768 B.
// NOTE (round-5 post-mortem): __launch_bounds__(256,4) caps VGPR at 128 but dist needs
// ~170 live -> accumulator spill (WRITE 45->459MB, 43->232us). The (256,2) is LOAD-BEARING.
// NOTE (round-7 post-mortem): full-symmetric (no mirror) REGRESSED — per-block latency
// ~constant, 1.9x work -> 1.5x time. Triangular + mirror is the right form.
__global__ __launch_bounds__(256, 2)
void qkv_dist(const hb* __restrict__ A, const hb* __restrict__ Bt,
              const void* __restrict__ bq, const void* __restrict__ bk, const void* __restrict__ bv,
              hb* __restrict__ qkvB,
              const hb* __restrict__ ph, const hb* __restrict__ pl,
              const float* __restrict__ p2, const void* __restrict__ cp,
              float* __restrict__ argb, const int* __restrict__ fmflag) {
    __shared__ float TmS[8192];   // 32768 B
    const int fm = *fmflag;
    const int tid = threadIdx.x, lane = tid & 63, wave = tid >> 6;

    if (blockIdx.x < 272) {
        // ---------------- dist: fused hi/lo, triangular, chunked LDS-transposed mirror ----------------
        constexpr int BK = 32, LDSW = 32;          // no pad; swizzled chunks
        constexpr int KI = DDIM / BK;
        constexpr int TSH = 128 * LDSW;            // 4096 shorts per tile
        short* Sb = (short*)TmS;
        float* Tm = TmS;           // 32x132 f32 chunk buffer (16896 B), reuses staging after K-loop

        const float c = ld_scalar(cp, fm);
        const int bb = blockIdx.x / 136;
        const float* p2b = p2 + bb * NTOK;
        const size_t rb = (size_t)bb * NTOK;
        float* out = argb + (size_t)bb * NTOK * NTOK;
        int t = blockIdx.x % 136, bi = 0, rem = 16;
        while (t >= rem) { t -= rem; bi++; rem = 16 - bi; }
        const int bj = bi + t;
        const int i0 = bi * 128, j0 = bj * 128;
        const bool diag = (bi == bj);

        const int wy = wave >> 1, wx = wave & 1;
        const int r0 = tid >> 2, cch = tid & 3;    // row 0..63, chunk 0..3
        const int lm = lane & 15;
        const int wslot = (cch ^ ((r0 >> 1) & 3)) * 8;
        const int rslot = (((lane >> 4) ^ ((lm >> 1) & 3))) * 8;
        const int c0g = cch * 8;                   // global k-offset of this lane's chunk

        const hb* src[4] = { ph + (rb + i0) * DDIM, pl + (rb + i0) * DDIM,
                             ph + (rb + j0) * DDIM, pl + (rb + j0) * DDIM };

        f4v acc_hh[4][4], acc_x[4][4];
        #pragma unroll
        for (int i = 0; i < 4; ++i)
            #pragma unroll
            for (int j = 0; j < 4; ++j) { acc_hh[i][j] = (f4v){0.f,0.f,0.f,0.f}; acc_x[i][j] = (f4v){0.f,0.f,0.f,0.f}; }

        s8v pf[4][2];
        #pragma unroll
        for (int tt = 0; tt < 4; ++tt)
            #pragma unroll
            for (int g = 0; g < 2; ++g)
                pf[tt][g] = *(const s8v*)(src[tt] + (size_t)(r0 + 64 * g) * DDIM + c0g);

        for (int it = 0; it < KI; ++it) {
            __syncthreads();
            #pragma unroll
            for (int tt = 0; tt < 4; ++tt)
                #pragma unroll
                for (int g = 0; g < 2; ++g)
                    *(s8v*)(Sb + tt * TSH + (r0 + 64 * g) * LDSW + wslot) = pf[tt][g];
            if (it + 1 < KI) {
                const int kn = (it + 1) * BK;
                #pragma unroll
                for (int tt = 0; tt < 4; ++tt)
                    #pragma unroll
                    for (int g = 0; g < 2; ++g)
                        pf[tt][g] = *(const s8v*)(src[tt] + (size_t)(r0 + 64 * g) * DDIM + kn + c0g);
            }
            __syncthreads();
            s8v ah[4], al[4], bh[4], bl[4];
            #pragma unroll
            for (int f = 0; f < 4; ++f) {
                ah[f] = *(const s8v*)(Sb + 0 * TSH + (wy * 64 + f * 16 + lm) * LDSW + rslot);
                al[f] = *(const s8v*)(Sb + 1 * TSH + (wy * 64 + f * 16 + lm) * LDSW + rslot);
                bh[f] = *(const s8v*)(Sb + 2 * TSH + (wx * 64 + f * 16 + lm) * LDSW + rslot);
                bl[f] = *(const s8v*)(Sb + 3 * TSH + (wx * 64 + f * 16 + lm) * LDSW + rslot);
            }
            #pragma unroll
            for (int fi = 0; fi < 4; ++fi)
                #pragma unroll
                for (int fj = 0; fj < 4; ++fj) {
                    acc_hh[fi][fj] = __builtin_amdgcn_mfma_f32_16x16x32_bf16(ah[fi], bh[fj], acc_hh[fi][fj], 0, 0, 0);
                    acc_x[fi][fj]  = __builtin_amdgcn_mfma_f32_16x16x32_bf16(ah[fi], bl[fj], acc_x[fi][fj], 0, 0, 0);
                    acc_x[fi][fj]  = __builtin_amdgcn_mfma_f32_16x16x32_bf16(al[fi], bh[fj], acc_x[fi][fj], 0, 0, 0);
                }
        }

        // pass 1: compute argv, write upper-triangle block directly, stash argv in acc_hh regs
        const int eibase = i0 + wy * 64 + (lane >> 4) * 4;
        const int ejbase = j0 + wx * 64 + lm;
        #pragma unroll
        for (int fi = 0; fi < 4; ++fi) {
            #pragma unroll
            for (int fj = 0; fj < 4; ++fj) {
                const int jj = ejbase + fj * 16;
                const float p2j = p2b[jj];
                #pragma unroll
                for (int r = 0; r < 4; ++r) {
                    const int ii = eibase + fi * 16 + r;
                    const float p2i = p2b[ii];
                    const float xy = acc_hh[fi][fj][r] + acc_x[fi][fj][r];
                    float diff = fmaxf(p2i + p2j - 2.f * xy, 0.f);
                    float den = fmaxf((1.f - c * p2i) * (1.f - c * p2j), 1e-8f);
                    float argv = 1.f + 2.f * c * diff / den;
                    out[(size_t)ii * NTOK + jj] = argv;
                    acc_hh[fi][fj][r] = argv;
                }
            }
        }
        // pass 2: mirrored block via 4 chunks of 32 rows through 32x132 f32 LDS
        if (!diag) {
            #pragma unroll
            for (int cc = 0; cc < 4; ++cc) {
                __syncthreads();
                if (wx == (cc >> 1)) {
                    #pragma unroll
                    for (int fjl = 0; fjl < 2; ++fjl) {
                        const int fj = (cc & 1) * 2 + fjl;
                        const int rT = fjl * 16 + lm;
                        #pragma unroll
                        for (int fi = 0; fi < 4; ++fi) {
                            const int cbase = wy * 64 + fi * 16 + (lane >> 4) * 4;
                            #pragma unroll
                            for (int r = 0; r < 4; ++r)
                                Tm[rT * 132 + cbase + r] = acc_hh[fi][fj][r];
                        }
                    }
                }
                __syncthreads();
                #pragma unroll
                for (int tt2 = 0; tt2 < 4; ++tt2) {
                    const int lin = tt2 * 256 + tid;
                    const int rowT = lin >> 5;
                    const int c4 = (lin & 31) * 4;
                    f4v v = *(const f4v*)(Tm + rowT * 132 + c4);
                    *(f4v*)(out + (size_t)(j0 + cc * 32 + rowT) * NTOK + i0 + c4) = v;
                }
            }
        }
    } else {
        // ---------------- qkv GEMM: TN=128, BK=32 dbuf (swizzled), ONE barrier per K-step ----------------
        constexpr int BK = 32, LDSW = 32;          // no pad; swizzled chunks
        constexpr int MAT = 128 * LDSW;            // 4096 shorts per matrix
        short* Ls = (short*)TmS;                   // 2 bufs x 2 mats x 4096 = 16384 shorts
        const int b = blockIdx.x - 272;
        const int m0 = (b / 12) * 128, n0 = (b % 12) * 128;
        const int wy = wave >> 1, wx = wave & 1;
        const int r0 = tid >> 2, cch = tid & 3;
        const int lm = lane & 15;
        const int wslot = (cch ^ ((r0 >> 1) & 3)) * 8;
        const int rslot = (((lane >> 4) ^ ((lm >> 1) & 3))) * 8;
        const int c0g = cch * 8;
        f4v acc[4][4];
        #pragma unroll
        for (int i = 0; i < 4; ++i)
            #pragma unroll
            for (int j = 0; j < 4; ++j) acc[i][j] = (f4v){0.f, 0.f, 0.f, 0.f};

        s8v an[2], bn[2];
        #pragma unroll
        for (int g = 0; g < 2; ++g) {
            an[g] = *(const s8v*)(A  + (size_t)(m0 + r0 + 64 * g) * 512 + c0g);
            bn[g] = *(const s8v*)(Bt + (size_t)(n0 + r0 + 64 * g) * 512 + c0g);
        }

        int p = 0;
        for (int k0 = 0; k0 < 512; k0 += BK) {
            short* As = Ls + p * (2 * MAT);
            short* Bs = As + MAT;
            #pragma unroll
            for (int g = 0; g < 2; ++g) {
                *(s8v*)(As + (r0 + 64 * g) * LDSW + wslot) = an[g];
                *(s8v*)(Bs + (r0 + 64 * g) * LDSW + wslot) = bn[g];
            }
            if (k0 + BK < 512) {
                const int kn = k0 + BK;
                #pragma unroll
                for (int g = 0; g < 2; ++g) {
                    an[g] = *(const s8v*)(A  + (size_t)(m0 + r0 + 64 * g) * 512 + kn + c0g);
                    bn[g] = *(const s8v*)(Bt + (size_t)(n0 + r0 + 64 * g) * 512 + kn + c0g);
                }
            }
            __syncthreads();
            s8v af[4], bf[4];
            #pragma unroll
            for (int f = 0; f < 4; ++f) {
                af[f] = *(const s8v*)(As + (wy * 64 + f * 16 + lm) * LDSW + rslot);
                bf[f] = *(const s8v*)(Bs + (wx * 64 + f * 16 + lm) * LDSW + rslot);
            }
            #pragma unroll
            for (int fi = 0; fi < 4; ++fi)
                #pragma unroll
                for (int fj = 0; fj < 4; ++fj)
                    acc[fi][fj] = __builtin_amdgcn_mfma_f32_16x16x32_bf16(af[fi], bf[fj], acc[fi][fj], 0, 0, 0);
            p ^= 1;
        }

        const int embase = m0 + wy * 64 + (lane >> 4) * 4;
        const int enbase = n0 + wx * 64 + lm;
        #pragma unroll
        for (int fi = 0; fi < 4; ++fi) {
            #pragma unroll
            for (int fj = 0; fj < 4; ++fj) {
                const int n = enbase + fj * 16;
                const void* bp = (n < 512) ? bq : ((n < 1024) ? bk : bv);
                const float bias = ldin(bp, n & 511, fm);
                #pragma unroll
                for (int r = 0; r < 4; ++r) {
                    const int m = embase + fi * 16 + r;
                    qkvB[(size_t)m * 1536 + n] = __float2bfloat16(acc[fi][fj][r] + bias);
                }
            }
        }
    }
}

// ---------------- fused top-16 + attention: TWO waves per row ----------------
// Round-9: topk was grid-limited (1024 blocks = 16 waves/CU, Occupancy 31%). Split each
// row's top-16 across 2 waves (1024 elems, 16 keys/lane each): per-round tree 15 mins
// (was 31), 2x waves (8192 = 32/CU possible). Keeps the all-lane ILP-rich rebuild that
// round-4's lazy variant proved necessary. Two sorted 16-lists merged by rank (keys are
// distinct u64 -> strict compares total-order). Phase 1 runs redundantly on both waves
// of a pair (identical LDS writes, keeps barriers uniform); phases 2-5 even wave only.
// Round-6 WIN kept: scalar-switch clear (readfirstlane regid + s_cbranch switch).
__global__ __launch_bounds__(256)
void topk_attn(const float* __restrict__ argb,
               const void* __restrict__ pos, const hb* __restrict__ qkvB,
               const float* __restrict__ p2, const float* __restrict__ spos,
               const void* __restrict__ cp,
               const void* __restrict__ geo_s, const void* __restrict__ geo_b,
               const void* __restrict__ a_sc, const void* __restrict__ f_sc,
               hb* __restrict__ attnO, const int* __restrict__ fmflag) {
    const int fm = *fmflag;
    const int lane = threadIdx.x & 63, wv = threadIdx.x >> 6;
    const int rowL = wv >> 1, half = wv & 1;
    const int row = blockIdx.x * 2 + rowL;
    const int bb = row >> 11, r = row & (NTOK - 1);
    const int l16 = lane & 15, grp = lane >> 4;

    __shared__ ull lists[2][2][16];
    __shared__ ull merged[2][16];
    __shared__ float qgsS[2][DDIM];
    __shared__ float qS[2][DDIM];

    // ======== per-half top-16 (1024 elems, 16 keys/lane) ========
    const float* arow = argb + (size_t)bb * NTOK * NTOK + (size_t)r * NTOK + half * 1024;
    ull k[16];
    #pragma unroll
    for (int i = 0; i < 4; ++i) {
        f4v v = *(const f4v*)(arow + lane * 4 + i * 256);
        #pragma unroll
        for (int e = 0; e < 4; ++e) {
            const unsigned idx = lane * 4 + e + i * 256 + half * 1024;
            k[i * 4 + e] = ((ull)__float_as_uint(v[e]) << 32) | idx;
        }
    }
    ull res = ~0ull;
    for (int sel = 0; sel < KNN_K; ++sel) {
        ull t8[8];
        #pragma unroll
        for (int i = 0; i < 8; ++i) t8[i] = (k[2 * i] < k[2 * i + 1]) ? k[2 * i] : k[2 * i + 1];
        #pragma unroll
        for (int i = 0; i < 4; ++i) t8[i] = (t8[2 * i] < t8[2 * i + 1]) ? t8[2 * i] : t8[2 * i + 1];
        ull m01 = (t8[0] < t8[1]) ? t8[0] : t8[1];
        ull m23 = (t8[2] < t8[3]) ? t8[2] : t8[3];
        ull m = (m01 < m23) ? m01 : m23;
        #pragma unroll
        for (int mask = 1; mask < 64; mask <<= 1) {
            ull o = shfl_xor_u64(m, mask);
            m = (o < m) ? o : m;
        }
        if (lane == sel) res = m;
        // m is wave-uniform -> scalarize the clear (slot = within-half i*4+e)
        const unsigned widx = __builtin_amdgcn_readfirstlane((unsigned)m);
        const bool mine = (int)((widx >> 2) & 63) == lane;
        const int regid = (int)((((widx >> 8) & 3) << 2) | (widx & 3));
        switch (regid) {
#define CLR(RR) case RR: if (mine) k[RR] = ~0ull; break;
            CLR(0)  CLR(1)  CLR(2)  CLR(3)  CLR(4)  CLR(5)  CLR(6)  CLR(7)
            CLR(8)  CLR(9)  CLR(10) CLR(11) CLR(12) CLR(13) CLR(14) CLR(15)
#undef CLR
        }
    }
    if (lane < 16) lists[rowL][half][lane] = res;
    __syncthreads();

    // ======== merge two ascending 16-lists by rank (even wave) ========
    if (half == 0 && lane < 16) {
        const ull av = lists[rowL][0][lane];
        const ull bv = lists[rowL][1][lane];
        int ra = lane, rb = lane;
        #pragma unroll
        for (int j = 0; j < 16; ++j) {
            ra += (lists[rowL][1][j] < av) ? 1 : 0;
            rb += (lists[rowL][0][j] < bv) ? 1 : 0;
        }
        if (ra < 16) merged[rowL][ra] = av;
        if (rb < 16) merged[rowL][rb] = bv;
    }
    __syncthreads();

    const ull mres = (lane < 16) ? merged[rowL][lane] : ~0ull;
    const int nid = (int)(unsigned)mres;                         // lane<16: neighbor index
    const float argv_l = __uint_as_float((unsigned)(mres >> 32)); // lane<16: arg value

    // ======== attention ========
    float* qgsL = qgsS[rowL];
    float* qL = qS[rowL];

    const float c = ld_scalar(cp, fm);
    const float cs = fmaxf(c, 1e-20f);
    const float sc_c = sqrtf(fmaxf(c, 0.f));

    // ---- phase 1: q-row stats (8 dims/lane) — BOTH waves of the pair, identical writes ----
    const int d0 = lane * 8;
    float qq = 0.f, qgs_sum = 0.f, qgb = 0.f;
    {
        float pv[8], gs[8], gb[8];
        ld8(pos, (size_t)row * DDIM + d0, fm, pv);
        ld8(geo_s, d0, fm, gs);
        ld8(geo_b, d0, fm, gb);
        s8v qv = *(const s8v*)(qkvB + (size_t)row * 1536 + d0);
        f4v a0, a1, q0, q1;
        #pragma unroll
        for (int e = 0; e < 4; ++e) {
            float qe = bits2f(qv[e]);
            float ae = qe * gs[e];
            q0[e] = qe; a0[e] = ae;
            qq += ae * pv[e]; qgs_sum += ae; qgb += qe * gb[e];
        }
        #pragma unroll
        for (int e = 0; e < 4; ++e) {
            float qe = bits2f(qv[e + 4]);
            float ae = qe * gs[e + 4];
            q1[e] = qe; a1[e] = ae;
            qq += ae * pv[e + 4]; qgs_sum += ae; qgb += qe * gb[e + 4];
        }
        *(f4v*)(qgsL + d0) = a0; *(f4v*)(qgsL + d0 + 4) = a1;
        *(f4v*)(qL + d0) = q0;   *(f4v*)(qL + d0 + 4) = q1;
    }
    #pragma unroll
    for (int off = 32; off; off >>= 1) {
        qq += __shfl_down(qq, off);
        qgs_sum += __shfl_down(qgs_sum, off);
        qgb += __shfl_down(qgb, off);
    }
    const float QQ  = __shfl(qq, 0);
    const float QGS = __shfl(qgs_sum, 0);
    const float QGB = __shfl(qgb, 0);
    __syncthreads();   // qgsL/qL cross-lane visible (uniform: all 4 waves)

    if (half == 1) return;   // odd waves done (no further barriers below)

    // ---- phase 2: dots, 4 neighbors per 16-lane group ----
    float qkt[4], ftt[4];
    #pragma unroll
    for (int t = 0; t < 4; ++t) {
        const int kk = grp * 4 + t;
        const int j = __shfl(nid, kk);
        const size_t nro = (size_t)(bb * NTOK + j) * DDIM;
        const size_t nrk = (size_t)(bb * NTOK + j) * 1536 + 512;
        float qk = 0.f, feat = 0.f;
        if (fm) {
            #pragma unroll
            for (int i = 0; i < 8; ++i) {
                const int d = l16 * 4 + i * 64;
                f4v kp = *(const f4v*)((const float*)pos + nro + d);
                f4v qg = *(const f4v*)(qgsL + d);
                qk += qg[0] * kp[0] + qg[1] * kp[1] + qg[2] * kp[2] + qg[3] * kp[3];
            }
        } else {
            #pragma unroll
            for (int i = 0; i < 8; ++i) {
                const int d = l16 * 4 + i * 64;
                s4v kp4 = *(const s4v*)((const hb*)pos + nro + d);
                f4v qg = *(const f4v*)(qgsL + d);
                #pragma unroll
                for (int e = 0; e < 4; ++e) qk += qg[e] * bits2f(kp4[e]);
            }
        }
        #pragma unroll
        for (int i = 0; i < 4; ++i) {
            const int d = l16 * 8 + i * 128;
            s8v kv = *(const s8v*)(qkvB + nrk + d);
            f4v q0 = *(const f4v*)(qL + d);
            f4v q1 = *(const f4v*)(qL + d + 4);
            #pragma unroll
            for (int e = 0; e < 4; ++e)
                feat += q0[e] * bits2f(kv[e]) + q1[e] * bits2f(kv[e + 4]);
        }
        #pragma unroll
        for (int off = 8; off; off >>= 1) {
            qk += __shfl_down(qk, off, 16);
            feat += __shfl_down(feat, off, 16);
        }
        qkt[t] = qk; ftt[t] = feat;
    }
    const int src = (lane >> 2) << 4;
    float qa[4], fa[4];
    #pragma unroll
    for (int t = 0; t < 4; ++t) { qa[t] = __shfl(qkt[t], src); fa[t] = __shfl(ftt[t], src); }
    const int tsel = lane & 3;
    const float qk_f = tsel == 0 ? qa[0] : tsel == 1 ? qa[1] : tsel == 2 ? qa[2] : qa[3];
    const float ft_f = tsel == 0 ? fa[0] : tsel == 1 ? fa[1] : tsel == 2 ? fa[2] : fa[3];

    // ---- phase 3: score math on lanes 0..15 (kk = lane) ----
    float sc_v = 0.f;
    if (lane < KNN_K) {
        const int j = nid;
        const float p2i = p2[row], p2j = p2[bb * NTOK + j];
        const float sposi = spos[row], sposj = spos[bb * NTOK + j];
        const float argv = argv_l;
        const float den_d = fmaxf((1.f - c * p2i) * (1.f - c * p2j), 1e-8f);
        const float diff = (argv - 1.f) * den_d / (2.f * cs);
        const float xy = 0.5f * (p2i + p2j - diff);
        const float x2 = p2i, y2 = p2j;
        const float Af = 1.f - 2.f * c * xy + c * y2;
        const float Bf = 1.f - c * x2;
        float den = fmaxf(1.f - 2.f * c * xy + c * c * x2 * y2, 1e-8f);
        const float rden = 1.f / den;
        float n2 = fmaxf(Af * Af * x2 - 2.f * Af * Bf * xy + Bf * Bf * y2, 0.f) * rden * rden;
        const float ynorm = fmaxf(sqrtf(n2), 1e-8f);
        const float t_over = sc_c * ynorm;
        const float targ = fminf(t_over, 1.f - 1e-7f);
        const float scale = (targ > 0.f) ? (atanhf(targ) / t_over) : 1.f;
        const float S1 = scale * rden * (Bf * sposj - Af * sposi);
        const float mean = S1 * (1.f / DDIM);
        const float sq = scale * scale * n2;
        const float var = sq * (1.f / DDIM) - mean * mean;
        const float rstd = rsqrtf(fmaxf(var, 0.f) + 1e-6f);
        const float G = scale * rden * (Bf * qk_f - Af * QQ);
        const float align = rstd * (G - mean * QGS) + QGB;
        sc_v = ld_scalar(f_sc, fm) * ft_f + ld_scalar(a_sc, fm) * align;
    }

    // ---- phase 4: softmax weights (redundant per-lane, shuffle-gathered) ----
    float s_t[16];
    #pragma unroll
    for (int t = 0; t < 16; ++t) s_t[t] = __shfl(sc_v, t);
    float mx = s_t[0];
    #pragma unroll
    for (int t = 1; t < 16; ++t) mx = fmaxf(mx, s_t[t]);
    float wsum = 0.f;
    #pragma unroll
    for (int t = 0; t < 16; ++t) { s_t[t] = expf(s_t[t] - mx); wsum += s_t[t]; }
    const float rw = 1.f / wsum;

    // ---- phase 5: V combine, 8 dims/lane, vectorized gathers ----
    float acc[8];
    #pragma unroll
    for (int e = 0; e < 8; ++e) acc[e] = 0.f;
    #pragma unroll
    for (int t = 0; t < 16; ++t) {
        const int j = __shfl(nid, t);
        const float w = s_t[t] * rw;
        s8v vvv = *(const s8v*)(qkvB + (size_t)(bb * NTOK + j) * 1536 + 1024 + d0);
        #pragma unroll
        for (int e = 0; e < 8; ++e) acc[e] += w * bits2f(vvv[e]);
    }
    s8v o;
    #pragma unroll
    for (int e = 0; e < 8; ++e) o[e] = f2bs(acc[e]);
    *(s8v*)(attnO + (size_t)row * DDIM + d0) = o;
}

extern "C" void kernel_launch(void* const* d_in, const int* in_sizes, int n_in,
                              void* d_out, int out_size, void* d_ws, size_t ws_size,
                              hipStream_t stream) {
    const void* x    = d_in[0];
    const void* posb = d_in[1];
    const void* cb   = d_in[2];
    const void* Wq   = d_in[3];
    const void* bq   = d_in[4];
    const void* Wk   = d_in[5];
    const void* bk   = d_in[6];
    const void* Wv   = d_in[7];
    const void* bv   = d_in[8];
    const void* Wo   = d_in[9];
    const void* bo   = d_in[10];
    const void* W1   = d_in[11];
    const void* b1   = d_in[12];
    const void* W2   = d_in[13];
    const void* b2   = d_in[14];
    const void* ln2s = d_in[17];
    const void* ln2b = d_in[18];
    const void* geos = d_in[19];
    const void* geob = d_in[20];
    const void* asc  = d_in[21];
    const void* fsc  = d_in[22];
    const void* ln1s = d_in[15];
    const void* ln1b = d_in[16];

    float* wsf = (float*)d_ws;
    size_t off = 0;
    hb* xnB   = (hb*)(wsf + off); off += 1048576;   // 4096x512 bf16; later hbuf (LN2 out)
    hb* qkvB  = (hb*)(wsf + off); off += 3145728;   // 4096x1536 bf16
    float* p2 = wsf + off;        off += 4096;
    float* spos = wsf + off;      off += 4096;
    float* x1 = wsf + off;        off += 2097152;   // f32 4096x512
    float* argb = wsf + off;                         // 2 x NTOK^2 f32
    hb* hh    = (hb*)argb;        off += 8388608;   // hh overlays argb (dead by FFN)
    hb* ph    = (hb*)(wsf + off); off += 1048576;   // later attnO
    hb* pl    = (hb*)(wsf + off); off += 1048576;
    hb* WqkvT = (hb*)(wsf + off); off += 393216;    // 1536x512 bf16
    hb* WoT   = (hb*)(wsf + off); off += 131072;    // 512x512 bf16
    hb* W1T   = (hb*)(wsf + off); off += 524288;    // 2048x512 bf16
    hb* W2T   = (hb*)(wsf + off); off += 524288;    // 512x2048 bf16
    int* fmflag = (int*)(wsf + off); off += 16;
    hb* attnO = ph;
    hb* hbuf  = xnB;

    // 1. setup: all transposes + pos split + p2/spos + LN1 + fmflag publish
    setup_kernel<<<4096, 256, 0, stream>>>(posb, x, ln1s, ln1b, Wq, Wk, Wv, Wo, W1, W2,
                                           ph, pl, p2, spos, xnB, WqkvT, WoT, W1T, W2T, fmflag);
    // 2. fused: dist (272 blocks, triangular) || qkv GEMM (384 blocks), 32768 B LDS swizzled
    qkv_dist<<<656, 256, 0, stream>>>(xnB, WqkvT, bq, bk, bv, qkvB,
                                      ph, pl, p2, cb, argb, fmflag);
    // 3. fused top-16 + geometric attention (2 waves/row, 2 rows/block)
    topk_attn<<<2048, 256, 0, stream>>>(argb, posb, qkvB, p2, spos, cb,
                                        geos, geob, asc, fsc, attnO, fmflag);
    // 4. x1 = x + attn @ Wo + bo  (f32)
    gemm64<1><<<dim3(8, 64), 256, 0, stream>>>(attnO, WoT, bo, x, x1,
                                               512, 512, 512, 512, fmflag);
    // 5. LN2 -> bf16 (wave-per-row)
    ln_kernel<<<1024, 256, 0, stream>>>(x1, ln2s, ln2b, hbuf, fmflag);
    // 6. hh = gelu(h @ W1 + b1) -> bf16
    gemm64<2><<<dim3(32, 64), 256, 0, stream>>>(hbuf, W1T, b1, nullptr, hh,
                                                512, 512, 512, 2048, fmflag);
    // 7. out = x1 + hh @ W2 + b2
    gemm64<3><<<dim3(8, 64), 256, 0, stream>>>(hh, W2T, b2, x1, d_out,
                                               2048, 2048, 2048, 512, fmflag);

    (void)in_sizes; (void)n_in; (void)out_size; (void)ws_size;
}

// Round 10
// 252.131 us; speedup vs baseline: 1.0744x; 1.0744x over previous
//
#include <hip/hip_runtime.h>
#include <hip/hip_bf16.h>
#include <math.h>

#define NTOK 2048      // N
#define DDIM 512       // D
#define FDIM 2048      // F
#define KNN_K 16
#define ROWS 4096      // B*N

typedef __hip_bfloat16 hb;
typedef unsigned long long ull;
typedef short s8v __attribute__((ext_vector_type(8)));
typedef short s4v __attribute__((ext_vector_type(4)));
typedef float f4v __attribute__((ext_vector_type(4)));

__device__ __forceinline__ float b2f(hb h) { return __bfloat162float(h); }
__device__ __forceinline__ float bits2f(short s) {
    return __uint_as_float(((unsigned int)(unsigned short)s) << 16);
}

__device__ __forceinline__ float ldin(const void* p, size_t i, int f32m) {
    return f32m ? ((const float*)p)[i] : b2f(((const hb*)p)[i]);
}
__device__ __forceinline__ float ld_scalar(const void* p, int f32m) {
    return f32m ? *(const float*)p : b2f(*(const hb*)p);
}
__device__ __forceinline__ short f2bs(float v) {
    hb h = __float2bfloat16(v);
    short s; __builtin_memcpy(&s, &h, 2); return s;
}
__device__ __forceinline__ short hb2s(hb h) {
    short s; __builtin_memcpy(&s, &h, 2); return s;
}

// load 8 consecutive values (f32 or bf16 input), base must be 8-elem aligned
__device__ __forceinline__ void ld8(const void* p, size_t base, int fm, float* o) {
    if (fm) {
        f4v a = *(const f4v*)((const float*)p + base);
        f4v b = *(const f4v*)((const float*)p + base + 4);
        o[0]=a[0]; o[1]=a[1]; o[2]=a[2]; o[3]=a[3];
        o[4]=b[0]; o[5]=b[1]; o[6]=b[2]; o[7]=b[3];
    } else {
        s8v v = *(const s8v*)((const hb*)p + base);
        #pragma unroll
        for (int e = 0; e < 8; ++e) o[e] = bits2f(v[e]);
    }
}

// wave-uniform inline dtype detection; only setup_kernel pays this, publishes fmflag.
__device__ __forceinline__ int detect_fm(const void* x) {
    const unsigned short* u = (const unsigned short*)x;
    const int lane = threadIdx.x & 63;
    int bad = 0;
    #pragma unroll
    for (int t = 0; t < 16; ++t) {
        unsigned short h = u[lane * 16 + t];
        int e = (h >> 7) & 0xFF;
        if (e == 0xFF) bad++;
        else if (e >= 0x8E) bad++;
        else if (e != 0 && e <= 0x66) bad++;
    }
    #pragma unroll
    for (int off = 1; off < 64; off <<= 1) bad += __shfl_xor(bad, off);
    return bad > 100 ? 1 : 0;
}

__device__ __forceinline__ ull shfl_xor_u64(ull x, int mask) {
    unsigned lo = (unsigned)x, hi = (unsigned)(x >> 32);
    lo = __shfl_xor(lo, mask); hi = __shfl_xor(hi, mask);
    return ((ull)hi << 32) | lo;
}

// gelu via sigmoid form: 0.5x(1+tanh(v)) == x*sigmoid(2v)
__device__ __forceinline__ float gelu_f(float x) {
    float u = 1.5957691216057308f * x * (1.f + 0.044715f * x * x);
    return x / (1.f + __expf(-u));
}

// ---------------- transpose tile body ----------------
__device__ __forceinline__ void tr_tile(const void* src, hb* dst, int K, int N,
                                        int k0, int n0, int fm) {
    __shared__ float t[32][33];
    const int tx = threadIdx.x & 31, ty = threadIdx.x >> 5;   // 32 x 8
    #pragma unroll
    for (int r = 0; r < 32; r += 8)
        t[ty + r][tx] = ldin(src, (size_t)(k0 + ty + r) * N + n0 + tx, fm);
    __syncthreads();
    #pragma unroll
    for (int r = 0; r < 32; r += 8)
        dst[(size_t)(n0 + ty + r) * K + k0 + tx] = __float2bfloat16(t[tx][ty + r]);
}

// ---------------- setup: weight transposes + pos split + p2 + spos + LN1 ----------------
__global__ void setup_kernel(const void* __restrict__ pos, const void* __restrict__ x,
                             const void* __restrict__ ln1s, const void* __restrict__ ln1b,
                             const void* __restrict__ Wq, const void* __restrict__ Wk,
                             const void* __restrict__ Wv, const void* __restrict__ Wo,
                             const void* __restrict__ W1, const void* __restrict__ W2,
                             hb* __restrict__ ph, hb* __restrict__ pl,
                             float* __restrict__ p2, float* __restrict__ spos,
                             hb* __restrict__ xnB,
                             hb* __restrict__ WqkvT, hb* __restrict__ WoT,
                             hb* __restrict__ W1T, hb* __restrict__ W2T,
                             int* __restrict__ fmflag) {
    const int fm = detect_fm(x);
    const int bx = blockIdx.x;
    if (bx == 0 && threadIdx.x == 0) *fmflag = fm;
    if (bx < 1024) {
        const int seg = bx >> 8, t = bx & 255;
        const int n0 = (t & 15) * 32, k0 = (t >> 4) * 32;
        const void* src = (seg == 0) ? Wq : (seg == 1) ? Wk : (seg == 2) ? Wv : Wo;
        hb* dst = (seg == 3) ? WoT : (WqkvT + (size_t)seg * 512 * 512);
        tr_tile(src, dst, 512, 512, k0, n0, fm);
    } else if (bx < 3072) {
        const int b = bx - 1024;
        if (b < 1024) {
            const int n0 = (b & 63) * 32, k0 = (b >> 6) * 32;
            tr_tile(W1, W1T, 512, 2048, k0, n0, fm);
        } else {
            const int b2 = b - 1024;
            const int n0 = (b2 & 15) * 32, k0 = (b2 >> 4) * 32;
            tr_tile(W2, W2T, 2048, 512, k0, n0, fm);
        }
    } else {
        const int idx = bx - 3072;
        const int lane = threadIdx.x & 63, wv = threadIdx.x >> 6;
        const int row = idx * 4 + wv;
        const int d0 = lane * 8;
        float pv[8], xv[8];
        ld8(pos, (size_t)row * DDIM + d0, fm, pv);
        ld8(x,   (size_t)row * DDIM + d0, fm, xv);
        s8v phv, plv;
        float s2 = 0.f, s1 = 0.f, sum = 0.f, sq = 0.f;
        #pragma unroll
        for (int e = 0; e < 8; ++e) {
            float v = pv[e];
            hb h = __float2bfloat16(v);
            phv[e] = hb2s(h);
            plv[e] = f2bs(v - b2f(h));
            s2 += v * v; s1 += v;
            sum += xv[e]; sq += xv[e] * xv[e];
        }
        *(s8v*)(ph + (size_t)row * DDIM + d0) = phv;
        *(s8v*)(pl + (size_t)row * DDIM + d0) = plv;
        #pragma unroll
        for (int off = 32; off; off >>= 1) {
            s2 += __shfl_down(s2, off); s1 += __shfl_down(s1, off);
            sum += __shfl_down(sum, off); sq += __shfl_down(sq, off);
        }
        if (lane == 0) { p2[row] = s2; spos[row] = s1; }
        const float ts = __shfl(sum, 0), tq = __shfl(sq, 0);
        const float mean = ts * (1.f / DDIM);
        const float var = tq * (1.f / DDIM) - mean * mean;
        const float rstd = rsqrtf(var + 1e-6f);
        float sv[8], bv2[8];
        ld8(ln1s, d0, fm, sv);
        ld8(ln1b, d0, fm, bv2);
        s8v xo;
        #pragma unroll
        for (int e = 0; e < 8; ++e)
            xo[e] = f2bs(sv[e] * (xv[e] - mean) * rstd + bv2[e]);
        *(s8v*)(xnB + (size_t)row * DDIM + d0) = xo;
    }
}

// ---------------- LayerNorm (internal f32 in), wave-per-row ----------------
__global__ void ln_kernel(const float* __restrict__ xin,
                          const void* __restrict__ s, const void* __restrict__ b,
                          hb* __restrict__ y, const int* __restrict__ fmflag) {
    const int m = *fmflag;
    const int lane = threadIdx.x & 63, wv = threadIdx.x >> 6;
    const int row = blockIdx.x * 4 + wv;
    const int d0 = lane * 8;
    const float* xp = xin + (size_t)row * DDIM + d0;
    f4v a = *(const f4v*)xp, c4 = *(const f4v*)(xp + 4);
    float v[8] = {a[0], a[1], a[2], a[3], c4[0], c4[1], c4[2], c4[3]};
    float sum = 0.f, sq = 0.f;
    #pragma unroll
    for (int e = 0; e < 8; ++e) { sum += v[e]; sq += v[e] * v[e]; }
    #pragma unroll
    for (int off = 32; off; off >>= 1) { sum += __shfl_down(sum, off); sq += __shfl_down(sq, off); }
    const float ts = __shfl(sum, 0), tq = __shfl(sq, 0);
    const float mean = ts * (1.f / DDIM);
    const float var = tq * (1.f / DDIM) - mean * mean;
    const float rstd = rsqrtf(var + 1e-6f);
    float sv[8], bv[8];
    ld8(s, d0, m, sv);
    ld8(b, d0, m, bv);
    s8v o;
    #pragma unroll
    for (int e = 0; e < 8; ++e) o[e] = f2bs(sv[e] * (v[e] - mean) * rstd + bv[e]);
    *(s8v*)(y + (size_t)row * DDIM + d0) = o;
}

// ================ 64x64-tile GEMM: dbuf LDS, ONE barrier per K-step, 4 blocks/CU ================
template<int EPI>
__global__ __launch_bounds__(256, 4)
void gemm64(const hb* __restrict__ A, const hb* __restrict__ Bt,
            const void* __restrict__ bp0, const void* __restrict__ res,
            void* __restrict__ C, int K, int lda, int ldb, int ldc,
            const int* __restrict__ fmflag) {
    constexpr int BK = 64, LDSW = BK + 8;     // 72 shorts/row
    constexpr int MAT = 64 * LDSW;            // 4608 shorts per matrix tile
    __shared__ short Ls[2 * 2 * MAT];         // 36864 B
    const int fm = *fmflag;
    const int tid = threadIdx.x, lane = tid & 63, wave = tid >> 6;
    const int wy = wave >> 1, wx = wave & 1;
    const int m0 = blockIdx.y * 64, n0 = blockIdx.x * 64;
    const int r0 = tid >> 3, c0 = (tid & 7) * 8;
    const int lm = lane & 15, lk = (lane >> 4) * 8;
    f4v acc[2][2];
    #pragma unroll
    for (int i = 0; i < 2; ++i)
        #pragma unroll
        for (int j = 0; j < 2; ++j) acc[i][j] = (f4v){0.f, 0.f, 0.f, 0.f};

    s8v an[2], bn[2];
    #pragma unroll
    for (int g = 0; g < 2; ++g) {
        an[g] = *(const s8v*)(A  + (size_t)(m0 + r0 + 32 * g) * lda + c0);
        bn[g] = *(const s8v*)(Bt + (size_t)(n0 + r0 + 32 * g) * ldb + c0);
    }

    int p = 0;
    for (int k0 = 0; k0 < K; k0 += BK) {
        short* As = Ls + p * (2 * MAT);
        short* Bs = As + MAT;
        #pragma unroll
        for (int g = 0; g < 2; ++g) {
            *(s8v*)(As + (r0 + 32 * g) * LDSW + c0) = an[g];
            *(s8v*)(Bs + (r0 + 32 * g) * LDSW + c0) = bn[g];
        }
        if (k0 + BK < K) {
            const int kn = k0 + BK;
            #pragma unroll
            for (int g = 0; g < 2; ++g) {
                an[g] = *(const s8v*)(A  + (size_t)(m0 + r0 + 32 * g) * lda + kn + c0);
                bn[g] = *(const s8v*)(Bt + (size_t)(n0 + r0 + 32 * g) * ldb + kn + c0);
            }
        }
        __syncthreads();
        #pragma unroll
        for (int kc = 0; kc < BK; kc += 32) {
            s8v af[2], bf[2];
            #pragma unroll
            for (int f = 0; f < 2; ++f) {
                af[f] = *(const s8v*)(As + (wy * 32 + f * 16 + lm) * LDSW + kc + lk);
                bf[f] = *(const s8v*)(Bs + (wx * 32 + f * 16 + lm) * LDSW + kc + lk);
            }
            #pragma unroll
            for (int fi = 0; fi < 2; ++fi)
                #pragma unroll
                for (int fj = 0; fj < 2; ++fj)
                    acc[fi][fj] = __builtin_amdgcn_mfma_f32_16x16x32_bf16(af[fi], bf[fj], acc[fi][fj], 0, 0, 0);
        }
        p ^= 1;
    }

    const int embase = m0 + wy * 32 + (lane >> 4) * 4;
    const int enbase = n0 + wx * 32 + lm;
    #pragma unroll
    for (int fi = 0; fi < 2; ++fi) {
        #pragma unroll
        for (int fj = 0; fj < 2; ++fj) {
            const int n = enbase + fj * 16;
            const float bias = ldin(bp0, n, fm);
            #pragma unroll
            for (int r = 0; r < 4; ++r) {
                const int m = embase + fi * 16 + r;
                float val = acc[fi][fj][r];
                size_t ci = (size_t)m * ldc + n;
                if (EPI == 1) {
                    val += bias + ldin(res, (size_t)m * 512 + n, fm);
                    ((float*)C)[ci] = val;
                } else if (EPI == 2) {
                    val = gelu_f(val + bias);
                    ((hb*)C)[ci] = __float2bfloat16(val);
                } else {
                    val += bias + ((const float*)res)[(size_t)m * 512 + n];
                    if (fm) ((float*)C)[ci] = val;
                    else ((hb*)C)[ci] = __float2bfloat16(val);
                }
            }
        }
    }
}

// ================ fused launch: dist (blocks 0..271, triangular) || qkv GEMM (272..655) ================
// Round-8 WIN: XOR-swizzled LDS, no padding. LDS 32768 B.
// Round-10: dist tail runs at ~1 block/CU (272 blocks, gemm side exits early; measured
// occupancy 14% = one 4-wave block) -> latency hiding must be intra-block. Prefetch
// depth deepened 1 -> 2 iterations (unroll-by-2, pfA/pfB register sets, no copies):
// slack ~1200cy covers L3 latency. +32 VGPR, fine under (256,2).
// NOTE (round-5): __launch_bounds__(256,4) spills dist accumulators. (256,2) LOAD-BEARING.
// NOTE (round-7): full-symmetric regressed; triangular + mirror is the right form.
__global__ __launch_bounds__(256, 2)
void qkv_dist(const hb* __restrict__ A, const hb* __restrict__ Bt,
              const void* __restrict__ bq, const void* __restrict__ bk, const void* __restrict__ bv,
              hb* __restrict__ qkvB,
              const hb* __restrict__ ph, const hb* __restrict__ pl,
              const float* __restrict__ p2, const void* __restrict__ cp,
              float* __restrict__ argb, const int* __restrict__ fmflag) {
    __shared__ float TmS[8192];   // 32768 B
    const int fm = *fmflag;
    const int tid = threadIdx.x, lane = tid & 63, wave = tid >> 6;

    if (blockIdx.x < 272) {
        // ---------------- dist: fused hi/lo, triangular, 2-deep prefetch ----------------
        constexpr int BK = 32, LDSW = 32;          // no pad; swizzled chunks
        constexpr int KI = DDIM / BK;
        constexpr int TSH = 128 * LDSW;            // 4096 shorts per tile
        short* Sb = (short*)TmS;
        float* Tm = TmS;           // 32x132 f32 chunk buffer, reuses staging after K-loop

        const float c = ld_scalar(cp, fm);
        const int bb = blockIdx.x / 136;
        const float* p2b = p2 + bb * NTOK;
        const size_t rb = (size_t)bb * NTOK;
        float* out = argb + (size_t)bb * NTOK * NTOK;
        int t = blockIdx.x % 136, bi = 0, rem = 16;
        while (t >= rem) { t -= rem; bi++; rem = 16 - bi; }
        const int bj = bi + t;
        const int i0 = bi * 128, j0 = bj * 128;
        const bool diag = (bi == bj);

        const int wy = wave >> 1, wx = wave & 1;
        const int r0 = tid >> 2, cch = tid & 3;    // row 0..63, chunk 0..3
        const int lm = lane & 15;
        const int wslot = (cch ^ ((r0 >> 1) & 3)) * 8;
        const int rslot = (((lane >> 4) ^ ((lm >> 1) & 3))) * 8;
        const int c0g = cch * 8;                   // global k-offset of this lane's chunk

        const hb* src[4] = { ph + (rb + i0) * DDIM, pl + (rb + i0) * DDIM,
                             ph + (rb + j0) * DDIM, pl + (rb + j0) * DDIM };

        f4v acc_hh[4][4], acc_x[4][4];
        #pragma unroll
        for (int i = 0; i < 4; ++i)
            #pragma unroll
            for (int j = 0; j < 4; ++j) { acc_hh[i][j] = (f4v){0.f,0.f,0.f,0.f}; acc_x[i][j] = (f4v){0.f,0.f,0.f,0.f}; }

        s8v pfA[4][2], pfB[4][2];
        #pragma unroll
        for (int tt = 0; tt < 4; ++tt)
            #pragma unroll
            for (int g = 0; g < 2; ++g) {
                pfA[tt][g] = *(const s8v*)(src[tt] + (size_t)(r0 + 64 * g) * DDIM + c0g);
                pfB[tt][g] = *(const s8v*)(src[tt] + (size_t)(r0 + 64 * g) * DDIM + BK + c0g);
            }

        for (int it = 0; it < KI; it += 2) {
            // ---- sub-iter A: consume pfA(it), prefetch it+2 ----
            __syncthreads();
            #pragma unroll
            for (int tt = 0; tt < 4; ++tt)
                #pragma unroll
                for (int g = 0; g < 2; ++g)
                    *(s8v*)(Sb + tt * TSH + (r0 + 64 * g) * LDSW + wslot) = pfA[tt][g];
            if (it + 2 < KI) {
                const int kn = (it + 2) * BK;
                #pragma unroll
                for (int tt = 0; tt < 4; ++tt)
                    #pragma unroll
                    for (int g = 0; g < 2; ++g)
                        pfA[tt][g] = *(const s8v*)(src[tt] + (size_t)(r0 + 64 * g) * DDIM + kn + c0g);
            }
            __syncthreads();
            {
                s8v ah[4], al[4], bh[4], bl[4];
                #pragma unroll
                for (int f = 0; f < 4; ++f) {
                    ah[f] = *(const s8v*)(Sb + 0 * TSH + (wy * 64 + f * 16 + lm) * LDSW + rslot);
                    al[f] = *(const s8v*)(Sb + 1 * TSH + (wy * 64 + f * 16 + lm) * LDSW + rslot);
                    bh[f] = *(const s8v*)(Sb + 2 * TSH + (wx * 64 + f * 16 + lm) * LDSW + rslot);
                    bl[f] = *(const s8v*)(Sb + 3 * TSH + (wx * 64 + f * 16 + lm) * LDSW + rslot);
                }
                #pragma unroll
                for (int fi = 0; fi < 4; ++fi)
                    #pragma unroll
                    for (int fj = 0; fj < 4; ++fj) {
                        acc_hh[fi][fj] = __builtin_amdgcn_mfma_f32_16x16x32_bf16(ah[fi], bh[fj], acc_hh[fi][fj], 0, 0, 0);
                        acc_x[fi][fj]  = __builtin_amdgcn_mfma_f32_16x16x32_bf16(ah[fi], bl[fj], acc_x[fi][fj], 0, 0, 0);
                        acc_x[fi][fj]  = __builtin_amdgcn_mfma_f32_16x16x32_bf16(al[fi], bh[fj], acc_x[fi][fj], 0, 0, 0);
                    }
            }
            // ---- sub-iter B: consume pfB(it+1), prefetch it+3 ----
            __syncthreads();
            #pragma unroll
            for (int tt = 0; tt < 4; ++tt)
                #pragma unroll
                for (int g = 0; g < 2; ++g)
                    *(s8v*)(Sb + tt * TSH + (r0 + 64 * g) * LDSW + wslot) = pfB[tt][g];
            if (it + 3 < KI) {
                const int kn = (it + 3) * BK;
                #pragma unroll
                for (int tt = 0; tt < 4; ++tt)
                    #pragma unroll
                    for (int g = 0; g < 2; ++g)
                        pfB[tt][g] = *(const s8v*)(src[tt] + (size_t)(r0 + 64 * g) * DDIM + kn + c0g);
            }
            __syncthreads();
            {
                s8v ah[4], al[4], bh[4], bl[4];
                #pragma unroll
                for (int f = 0; f < 4; ++f) {
                    ah[f] = *(const s8v*)(Sb + 0 * TSH + (wy * 64 + f * 16 + lm) * LDSW + rslot);
                    al[f] = *(const s8v*)(Sb + 1 * TSH + (wy * 64 + f * 16 + lm) * LDSW + rslot);
                    bh[f] = *(const s8v*)(Sb + 2 * TSH + (wx * 64 + f * 16 + lm) * LDSW + rslot);
                    bl[f] = *(const s8v*)(Sb + 3 * TSH + (wx * 64 + f * 16 + lm) * LDSW + rslot);
                }
                #pragma unroll
                for (int fi = 0; fi < 4; ++fi)
                    #pragma unroll
                    for (int fj = 0; fj < 4; ++fj) {
                        acc_hh[fi][fj] = __builtin_amdgcn_mfma_f32_16x16x32_bf16(ah[fi], bh[fj], acc_hh[fi][fj], 0, 0, 0);
                        acc_x[fi][fj]  = __builtin_amdgcn_mfma_f32_16x16x32_bf16(ah[fi], bl[fj], acc_x[fi][fj], 0, 0, 0);
                        acc_x[fi][fj]  = __builtin_amdgcn_mfma_f32_16x16x32_bf16(al[fi], bh[fj], acc_x[fi][fj], 0, 0, 0);
                    }
            }
        }

        // pass 1: compute argv, write upper-triangle block directly, stash argv in acc_hh regs
        const int eibase = i0 + wy * 64 + (lane >> 4) * 4;
        const int ejbase = j0 + wx * 64 + lm;
        #pragma unroll
        for (int fi = 0; fi < 4; ++fi) {
            #pragma unroll
            for (int fj = 0; fj < 4; ++fj) {
                const int jj = ejbase + fj * 16;
                const float p2j = p2b[jj];
                #pragma unroll
                for (int r = 0; r < 4; ++r) {
                    const int ii = eibase + fi * 16 + r;
                    const float p2i = p2b[ii];
                    const float xy = acc_hh[fi][fj][r] + acc_x[fi][fj][r];
                    float diff = fmaxf(p2i + p2j - 2.f * xy, 0.f);
                    float den = fmaxf((1.f - c * p2i) * (1.f - c * p2j), 1e-8f);
                    float argv = 1.f + 2.f * c * diff / den;
                    out[(size_t)ii * NTOK + jj] = argv;
                    acc_hh[fi][fj][r] = argv;
                }
            }
        }
        // pass 2: mirrored block via 4 chunks of 32 rows through 32x132 f32 LDS
        if (!diag) {
            #pragma unroll
            for (int cc = 0; cc < 4; ++cc) {
                __syncthreads();
                if (wx == (cc >> 1)) {
                    #pragma unroll
                    for (int fjl = 0; fjl < 2; ++fjl) {
                        const int fj = (cc & 1) * 2 + fjl;
                        const int rT = fjl * 16 + lm;
                        #pragma unroll
                        for (int fi = 0; fi < 4; ++fi) {
                            const int cbase = wy * 64 + fi * 16 + (lane >> 4) * 4;
                            #pragma unroll
                            for (int r = 0; r < 4; ++r)
                                Tm[rT * 132 + cbase + r] = acc_hh[fi][fj][r];
                        }
                    }
                }
                __syncthreads();
                #pragma unroll
                for (int tt2 = 0; tt2 < 4; ++tt2) {
                    const int lin = tt2 * 256 + tid;
                    const int rowT = lin >> 5;
                    const int c4 = (lin & 31) * 4;
                    f4v v = *(const f4v*)(Tm + rowT * 132 + c4);
                    *(f4v*)(out + (size_t)(j0 + cc * 32 + rowT) * NTOK + i0 + c4) = v;
                }
            }
        }
    } else {
        // ---------------- qkv GEMM: TN=128, BK=32 dbuf (swizzled), ONE barrier per K-step ----------------
        constexpr int BK = 32, LDSW = 32;          // no pad; swizzled chunks
        constexpr int MAT = 128 * LDSW;            // 4096 shorts per matrix
        short* Ls = (short*)TmS;                   // 2 bufs x 2 mats x 4096 = 16384 shorts
        const int b = blockIdx.x - 272;
        const int m0 = (b / 12) * 128, n0 = (b % 12) * 128;
        const int wy = wave >> 1, wx = wave & 1;
        const int r0 = tid >> 2, cch = tid & 3;
        const int lm = lane & 15;
        const int wslot = (cch ^ ((r0 >> 1) & 3)) * 8;
        const int rslot = (((lane >> 4) ^ ((lm >> 1) & 3))) * 8;
        const int c0g = cch * 8;
        f4v acc[4][4];
        #pragma unroll
        for (int i = 0; i < 4; ++i)
            #pragma unroll
            for (int j = 0; j < 4; ++j) acc[i][j] = (f4v){0.f, 0.f, 0.f, 0.f};

        s8v an[2], bn[2];
        #pragma unroll
        for (int g = 0; g < 2; ++g) {
            an[g] = *(const s8v*)(A  + (size_t)(m0 + r0 + 64 * g) * 512 + c0g);
            bn[g] = *(const s8v*)(Bt + (size_t)(n0 + r0 + 64 * g) * 512 + c0g);
        }

        int p = 0;
        for (int k0 = 0; k0 < 512; k0 += BK) {
            short* As = Ls + p * (2 * MAT);
            short* Bs = As + MAT;
            #pragma unroll
            for (int g = 0; g < 2; ++g) {
                *(s8v*)(As + (r0 + 64 * g) * LDSW + wslot) = an[g];
                *(s8v*)(Bs + (r0 + 64 * g) * LDSW + wslot) = bn[g];
            }
            if (k0 + BK < 512) {
                const int kn = k0 + BK;
                #pragma unroll
                for (int g = 0; g < 2; ++g) {
                    an[g] = *(const s8v*)(A  + (size_t)(m0 + r0 + 64 * g) * 512 + kn + c0g);
                    bn[g] = *(const s8v*)(Bt + (size_t)(n0 + r0 + 64 * g) * 512 + kn + c0g);
                }
            }
            __syncthreads();
            s8v af[4], bf[4];
            #pragma unroll
            for (int f = 0; f < 4; ++f) {
                af[f] = *(const s8v*)(As + (wy * 64 + f * 16 + lm) * LDSW + rslot);
                bf[f] = *(const s8v*)(Bs + (wx * 64 + f * 16 + lm) * LDSW + rslot);
            }
            #pragma unroll
            for (int fi = 0; fi < 4; ++fi)
                #pragma unroll
                for (int fj = 0; fj < 4; ++fj)
                    acc[fi][fj] = __builtin_amdgcn_mfma_f32_16x16x32_bf16(af[fi], bf[fj], acc[fi][fj], 0, 0, 0);
            p ^= 1;
        }

        const int embase = m0 + wy * 64 + (lane >> 4) * 4;
        const int enbase = n0 + wx * 64 + lm;
        #pragma unroll
        for (int fi = 0; fi < 4; ++fi) {
            #pragma unroll
            for (int fj = 0; fj < 4; ++fj) {
                const int n = enbase + fj * 16;
                const void* bp = (n < 512) ? bq : ((n < 1024) ? bk : bv);
                const float bias = ldin(bp, n & 511, fm);
                #pragma unroll
                for (int r = 0; r < 4; ++r) {
                    const int m = embase + fi * 16 + r;
                    qkvB[(size_t)m * 1536 + n] = __float2bfloat16(acc[fi][fj][r] + bias);
                }
            }
        }
    }
}

// ---------------- fused top-16 + attention: wave-per-row (round-8 form, REVERTED) ----------------
// Round-9 post-mortem: 2-wave split REGRESSED (44.7->61.5us) — each half still runs 16
// rounds so aggregate work rose ~28%, occupancy didn't move, odd waves idled phases 2-5.
// Round-4 post-mortem: lazy-tournament topk REGRESSED (divergent serialized rebuild).
// Round-6 WIN: scalar-switch clear (readfirstlane regid + s_cbranch switch). Keep as is.
__global__ __launch_bounds__(256)
void topk_attn(const float* __restrict__ argb,
               const void* __restrict__ pos, const hb* __restrict__ qkvB,
               const float* __restrict__ p2, const float* __restrict__ spos,
               const void* __restrict__ cp,
               const void* __restrict__ geo_s, const void* __restrict__ geo_b,
               const void* __restrict__ a_sc, const void* __restrict__ f_sc,
               hb* __restrict__ attnO, const int* __restrict__ fmflag) {
    const int fm = *fmflag;
    const int lane = threadIdx.x & 63, wv = threadIdx.x >> 6;
    const int row = blockIdx.x * 4 + wv;
    const int bb = row >> 11, r = row & (NTOK - 1);
    const int l16 = lane & 15, grp = lane >> 4;

    // ======== top-16 ========
    const float* arow = argb + (size_t)bb * NTOK * NTOK + (size_t)r * NTOK;
    ull k[32];
    #pragma unroll
    for (int i = 0; i < 8; ++i) {
        f4v v = *(const f4v*)(arow + lane * 4 + i * 256);
        #pragma unroll
        for (int e = 0; e < 4; ++e) {
            const unsigned idx = lane * 4 + e + i * 256;
            k[i * 4 + e] = ((ull)__float_as_uint(v[e]) << 32) | idx;
        }
    }
    ull res = ~0ull;
    for (int sel = 0; sel < KNN_K; ++sel) {
        ull t16[16];
        #pragma unroll
        for (int i = 0; i < 16; ++i) t16[i] = (k[2 * i] < k[2 * i + 1]) ? k[2 * i] : k[2 * i + 1];
        #pragma unroll
        for (int i = 0; i < 8; ++i) t16[i] = (t16[2 * i] < t16[2 * i + 1]) ? t16[2 * i] : t16[2 * i + 1];
        #pragma unroll
        for (int i = 0; i < 4; ++i) t16[i] = (t16[2 * i] < t16[2 * i + 1]) ? t16[2 * i] : t16[2 * i + 1];
        ull m01 = (t16[0] < t16[1]) ? t16[0] : t16[1];
        ull m23 = (t16[2] < t16[3]) ? t16[2] : t16[3];
        ull m = (m01 < m23) ? m01 : m23;
        #pragma unroll
        for (int mask = 1; mask < 64; mask <<= 1) {
            ull o = shfl_xor_u64(m, mask);
            m = (o < m) ? o : m;
        }
        if (lane == sel) res = m;
        const unsigned widx = __builtin_amdgcn_readfirstlane((unsigned)m);
        const bool mine = (int)((widx >> 2) & 63) == lane;
        const int regid = (int)(((widx >> 8) << 2) | (widx & 3));
        switch (regid) {
#define CLR(RR) case RR: if (mine) k[RR] = ~0ull; break;
            CLR(0)  CLR(1)  CLR(2)  CLR(3)  CLR(4)  CLR(5)  CLR(6)  CLR(7)
            CLR(8)  CLR(9)  CLR(10) CLR(11) CLR(12) CLR(13) CLR(14) CLR(15)
            CLR(16) CLR(17) CLR(18) CLR(19) CLR(20) CLR(21) CLR(22) CLR(23)
            CLR(24) CLR(25) CLR(26) CLR(27) CLR(28) CLR(29) CLR(30) CLR(31)
#undef CLR
        }
    }
    const int nid = (int)(unsigned)res;                          // lane<16: neighbor index
    const float argv_l = __uint_as_float((unsigned)(res >> 32)); // lane<16: arg value

    // ======== attention ========
    __shared__ float qgsS[4][DDIM];
    __shared__ float qS[4][DDIM];
    float* qgsL = qgsS[wv];
    float* qL = qS[wv];

    const float c = ld_scalar(cp, fm);
    const float cs = fmaxf(c, 1e-20f);
    const float sc_c = sqrtf(fmaxf(c, 0.f));

    // ---- phase 1: q-row stats (8 dims/lane, vectorized) ----
    const int d0 = lane * 8;
    float qq = 0.f, qgs_sum = 0.f, qgb = 0.f;
    {
        float pv[8], gs[8], gb[8];
        ld8(pos, (size_t)row * DDIM + d0, fm, pv);
        ld8(geo_s, d0, fm, gs);
        ld8(geo_b, d0, fm, gb);
        s8v qv = *(const s8v*)(qkvB + (size_t)row * 1536 + d0);
        f4v a0, a1, q0, q1;
        #pragma unroll
        for (int e = 0; e < 4; ++e) {
            float qe = bits2f(qv[e]);
            float ae = qe * gs[e];
            q0[e] = qe; a0[e] = ae;
            qq += ae * pv[e]; qgs_sum += ae; qgb += qe * gb[e];
        }
        #pragma unroll
        for (int e = 0; e < 4; ++e) {
            float qe = bits2f(qv[e + 4]);
            float ae = qe * gs[e + 4];
            q1[e] = qe; a1[e] = ae;
            qq += ae * pv[e + 4]; qgs_sum += ae; qgb += qe * gb[e + 4];
        }
        *(f4v*)(qgsL + d0) = a0; *(f4v*)(qgsL + d0 + 4) = a1;
        *(f4v*)(qL + d0) = q0;   *(f4v*)(qL + d0 + 4) = q1;
    }
    #pragma unroll
    for (int off = 32; off; off >>= 1) {
        qq += __shfl_down(qq, off);
        qgs_sum += __shfl_down(qgs_sum, off);
        qgb += __shfl_down(qgb, off);
    }
    const float QQ  = __shfl(qq, 0);
    const float QGS = __shfl(qgs_sum, 0);
    const float QGB = __shfl(qgb, 0);
    __syncthreads();   // qgsL/qL cross-lane visible

    // ---- phase 2: dots, 4 neighbors per 16-lane group ----
    float qkt[4], ftt[4];
    #pragma unroll
    for (int t = 0; t < 4; ++t) {
        const int kk = grp * 4 + t;
        const int j = __shfl(nid, kk);
        const size_t nro = (size_t)(bb * NTOK + j) * DDIM;
        const size_t nrk = (size_t)(bb * NTOK + j) * 1536 + 512;
        float qk = 0.f, feat = 0.f;
        if (fm) {
            #pragma unroll
            for (int i = 0; i < 8; ++i) {
                const int d = l16 * 4 + i * 64;
                f4v kp = *(const f4v*)((const float*)pos + nro + d);
                f4v qg = *(const f4v*)(qgsL + d);
                qk += qg[0] * kp[0] + qg[1] * kp[1] + qg[2] * kp[2] + qg[3] * kp[3];
            }
        } else {
            #pragma unroll
            for (int i = 0; i < 8; ++i) {
                const int d = l16 * 4 + i * 64;
                s4v kp4 = *(const s4v*)((const hb*)pos + nro + d);
                f4v qg = *(const f4v*)(qgsL + d);
                #pragma unroll
                for (int e = 0; e < 4; ++e) qk += qg[e] * bits2f(kp4[e]);
            }
        }
        #pragma unroll
        for (int i = 0; i < 4; ++i) {
            const int d = l16 * 8 + i * 128;
            s8v kv = *(const s8v*)(qkvB + nrk + d);
            f4v q0 = *(const f4v*)(qL + d);
            f4v q1 = *(const f4v*)(qL + d + 4);
            #pragma unroll
            for (int e = 0; e < 4; ++e)
                feat += q0[e] * bits2f(kv[e]) + q1[e] * bits2f(kv[e + 4]);
        }
        #pragma unroll
        for (int off = 8; off; off >>= 1) {
            qk += __shfl_down(qk, off, 16);
            feat += __shfl_down(feat, off, 16);
        }
        qkt[t] = qk; ftt[t] = feat;
    }
    const int src = (lane >> 2) << 4;
    float qa[4], fa[4];
    #pragma unroll
    for (int t = 0; t < 4; ++t) { qa[t] = __shfl(qkt[t], src); fa[t] = __shfl(ftt[t], src); }
    const int tsel = lane & 3;
    const float qk_f = tsel == 0 ? qa[0] : tsel == 1 ? qa[1] : tsel == 2 ? qa[2] : qa[3];
    const float ft_f = tsel == 0 ? fa[0] : tsel == 1 ? fa[1] : tsel == 2 ? fa[2] : fa[3];

    // ---- phase 3: score math on lanes 0..15 (kk = lane) ----
    float sc_v = 0.f;
    if (lane < KNN_K) {
        const int j = nid;
        const float p2i = p2[row], p2j = p2[bb * NTOK + j];
        const float sposi = spos[row], sposj = spos[bb * NTOK + j];
        const float argv = argv_l;
        const float den_d = fmaxf((1.f - c * p2i) * (1.f - c * p2j), 1e-8f);
        const float diff = (argv - 1.f) * den_d / (2.f * cs);
        const float xy = 0.5f * (p2i + p2j - diff);
        const float x2 = p2i, y2 = p2j;
        const float Af = 1.f - 2.f * c * xy + c * y2;
        const float Bf = 1.f - c * x2;
        float den = fmaxf(1.f - 2.f * c * xy + c * c * x2 * y2, 1e-8f);
        const float rden = 1.f / den;
        float n2 = fmaxf(Af * Af * x2 - 2.f * Af * Bf * xy + Bf * Bf * y2, 0.f) * rden * rden;
        const float ynorm = fmaxf(sqrtf(n2), 1e-8f);
        const float t_over = sc_c * ynorm;
        const float targ = fminf(t_over, 1.f - 1e-7f);
        const float scale = (targ > 0.f) ? (atanhf(targ) / t_over) : 1.f;
        const float S1 = scale * rden * (Bf * sposj - Af * sposi);
        const float mean = S1 * (1.f / DDIM);
        const float sq = scale * scale * n2;
        const float var = sq * (1.f / DDIM) - mean * mean;
        const float rstd = rsqrtf(fmaxf(var, 0.f) + 1e-6f);
        const float G = scale * rden * (Bf * qk_f - Af * QQ);
        const float align = rstd * (G - mean * QGS) + QGB;
        sc_v = ld_scalar(f_sc, fm) * ft_f + ld_scalar(a_sc, fm) * align;
    }

    // ---- phase 4: softmax weights (redundant per-lane, shuffle-gathered) ----
    float s_t[16];
    #pragma unroll
    for (int t = 0; t < 16; ++t) s_t[t] = __shfl(sc_v, t);
    float mx = s_t[0];
    #pragma unroll
    for (int t = 1; t < 16; ++t) mx = fmaxf(mx, s_t[t]);
    float wsum = 0.f;
    #pragma unroll
    for (int t = 0; t < 16; ++t) { s_t[t] = expf(s_t[t] - mx); wsum += s_t[t]; }
    const float rw = 1.f / wsum;

    // ---- phase 5: V combine, 8 dims/lane, vectorized gathers ----
    float acc[8];
    #pragma unroll
    for (int e = 0; e < 8; ++e) acc[e] = 0.f;
    #pragma unroll
    for (int t = 0; t < 16; ++t) {
        const int j = __shfl(nid, t);
        const float w = s_t[t] * rw;
        s8v vvv = *(const s8v*)(qkvB + (size_t)(bb * NTOK + j) * 1536 + 1024 + d0);
        #pragma unroll
        for (int e = 0; e < 8; ++e) acc[e] += w * bits2f(vvv[e]);
    }
    s8v o;
    #pragma unroll
    for (int e = 0; e < 8; ++e) o[e] = f2bs(acc[e]);
    *(s8v*)(attnO + (size_t)row * DDIM + d0) = o;
}

extern "C" void kernel_launch(void* const* d_in, const int* in_sizes, int n_in,
                              void* d_out, int out_size, void* d_ws, size_t ws_size,
                              hipStream_t stream) {
    const void* x    = d_in[0];
    const void* posb = d_in[1];
    const void* cb   = d_in[2];
    const void* Wq   = d_in[3];
    const void* bq   = d_in[4];
    const void* Wk   = d_in[5];
    const void* bk   = d_in[6];
    const void* Wv   = d_in[7];
    const void* bv   = d_in[8];
    const void* Wo   = d_in[9];
    const void* bo   = d_in[10];
    const void* W1   = d_in[11];
    const void* b1   = d_in[12];
    const void* W2   = d_in[13];
    const void* b2   = d_in[14];
    const void* ln2s = d_in[17];
    const void* ln2b = d_in[18];
    const void* geos = d_in[19];
    const void* geob = d_in[20];
    const void* asc  = d_in[21];
    const void* fsc  = d_in[22];
    const void* ln1s = d_in[15];
    const void* ln1b = d_in[16];

    float* wsf = (float*)d_ws;
    size_t off = 0;
    hb* xnB   = (hb*)(wsf + off); off += 1048576;   // 4096x512 bf16; later hbuf (LN2 out)
    hb* qkvB  = (hb*)(wsf + off); off += 3145728;   // 4096x1536 bf16
    float* p2 = wsf + off;        off += 4096;
    float* spos = wsf + off;      off += 4096;
    float* x1 = wsf + off;        off += 2097152;   // f32 4096x512
    float* argb = wsf + off;                         // 2 x NTOK^2 f32
    hb* hh    = (hb*)argb;        off += 8388608;   // hh overlays argb (dead by FFN)
    hb* ph    = (hb*)(wsf + off); off += 1048576;   // later attnO
    hb* pl    = (hb*)(wsf + off); off += 1048576;
    hb* WqkvT = (hb*)(wsf + off); off += 393216;    // 1536x512 bf16
    hb* WoT   = (hb*)(wsf + off); off += 131072;    // 512x512 bf16
    hb* W1T   = (hb*)(wsf + off); off += 524288;    // 2048x512 bf16
    hb* W2T   = (hb*)(wsf + off); off += 524288;    // 512x2048 bf16
    int* fmflag = (int*)(wsf + off); off += 16;
    hb* attnO = ph;
    hb* hbuf  = xnB;

    // 1. setup: all transposes + pos split + p2/spos + LN1 + fmflag publish
    setup_kernel<<<4096, 256, 0, stream>>>(posb, x, ln1s, ln1b, Wq, Wk, Wv, Wo, W1, W2,
                                           ph, pl, p2, spos, xnB, WqkvT, WoT, W1T, W2T, fmflag);
    // 2. fused: dist (272 blocks, triangular, 2-deep prefetch) || qkv GEMM (384 blocks)
    qkv_dist<<<656, 256, 0, stream>>>(xnB, WqkvT, bq, bk, bv, qkvB,
                                      ph, pl, p2, cb, argb, fmflag);
    // 3. fused top-16 + geometric attention (wave-per-row, round-8 form)
    topk_attn<<<1024, 256, 0, stream>>>(argb, posb, qkvB, p2, spos, cb,
                                        geos, geob, asc, fsc, attnO, fmflag);
    // 4. x1 = x + attn @ Wo + bo  (f32)
    gemm64<1><<<dim3(8, 64), 256, 0, stream>>>(attnO, WoT, bo, x, x1,
                                               512, 512, 512, 512, fmflag);
    // 5. LN2 -> bf16 (wave-per-row)
    ln_kernel<<<1024, 256, 0, stream>>>(x1, ln2s, ln2b, hbuf, fmflag);
    // 6. hh = gelu(h @ W1 + b1) -> bf16
    gemm64<2><<<dim3(32, 64), 256, 0, stream>>>(hbuf, W1T, b1, nullptr, hh,
                                                512, 512, 512, 2048, fmflag);
    // 7. out = x1 + hh @ W2 + b2
    gemm64<3><<<dim3(8, 64), 256, 0, stream>>>(hh, W2T, b2, x1, d_out,
                                               2048, 2048, 2048, 512, fmflag);

    (void)in_sizes; (void)n_in; (void)out_size; (void)ws_size;
}